// Round 1
// baseline (190.017 us; speedup 1.0000x reference)
//
#include <hip/hip_runtime.h>

#define IN   128
#define HID  16
#define OUT  64

// K1: xsxn[i][0..15] = x[i,:] @ W_self1 ; xsxn[i][16..31] = x[i,:] @ W_neigh1
__global__ void k_proj1(const float* __restrict__ x,
                        const float* __restrict__ Ws,
                        const float* __restrict__ Wn,
                        float* __restrict__ xsxn, int n) {
    __shared__ float lw[IN][32];   // 16 KB: combined [W_self1 | W_neigh1]
    __shared__ float lx[8][IN];    // 4 KB: 8 node rows
    int tid = threadIdx.x;  // 256 threads
    for (int i = tid; i < IN * 32; i += 256) {
        int k = i >> 5, j = i & 31;
        lw[k][j] = (j < HID) ? Ws[k * HID + j] : Wn[k * HID + (j - 16)];
    }
    int node0 = blockIdx.x * 8;
    for (int i = tid; i < 8 * IN; i += 256) {
        int r = i >> 7, c = i & 127;
        int node = node0 + r;
        lx[r][c] = (node < n) ? x[(size_t)node * IN + c] : 0.f;
    }
    __syncthreads();
    int r = tid >> 5;     // local node 0..7
    int j = tid & 31;     // output column 0..31
    int node = node0 + r;
    if (node >= n) return;
    float acc = 0.f;
    #pragma unroll
    for (int k = 0; k < IN; ++k) acc += lx[r][k] * lw[k][j];
    xsxn[(size_t)node * 32 + j] = acc;
}

// Scatter-add 16-dim messages: agg[dst[e]*16+d] += feat[src[e]*stride+off+d]
// Optionally accumulates degree (one add per edge, on d==0 thread).
__global__ void k_scatter(const int* __restrict__ src,
                          const int* __restrict__ dst,
                          const float* __restrict__ feat,
                          int stride, int off,
                          float* __restrict__ agg,
                          float* __restrict__ deg,   // may be null
                          int e) {
    int gid = blockIdx.x * blockDim.x + threadIdx.x;
    int eidx = gid >> 4;
    int d = gid & 15;
    if (eidx >= e) return;
    int s = src[eidx];
    int t = dst[eidx];
    float v = feat[(size_t)s * stride + off + d];
    atomicAdd(&agg[(size_t)t * HID + d], v);
    if (deg != nullptr && d == 0) atomicAdd(&deg[t], 1.0f);
}

// K3: h = relu(xs + agg1/deg + b1)
__global__ void k_finish1(const float* __restrict__ xsxn,
                          const float* __restrict__ agg1,
                          const float* __restrict__ deg,
                          const float* __restrict__ b1,
                          float* __restrict__ h, int n) {
    int gid = blockIdx.x * blockDim.x + threadIdx.x;
    if (gid >= n * HID) return;
    int i = gid >> 4, j = gid & 15;
    float dg = fmaxf(deg[i], 1.0f);
    float v = xsxn[(size_t)i * 32 + j] + agg1[gid] / dg + b1[j];
    h[gid] = fmaxf(v, 0.f);
}

// K5: out = h @ W_self2 + (agg2/deg) @ W_neigh2 + b2
__global__ void k_out(const float* __restrict__ h,
                      const float* __restrict__ agg2,
                      const float* __restrict__ deg,
                      const float* __restrict__ Ws2,   // [16,64]
                      const float* __restrict__ Wn2,   // [16,64]
                      const float* __restrict__ b2,
                      float* __restrict__ out, int n) {
    __shared__ float lws[HID][OUT];  // 4 KB
    __shared__ float lwn[HID][OUT];  // 4 KB
    int tid = threadIdx.x;  // 256
    for (int i = tid; i < HID * OUT; i += 256) {
        lws[i >> 6][i & 63] = Ws2[i];
        lwn[i >> 6][i & 63] = Wn2[i];
    }
    __syncthreads();
    int r = tid >> 6;     // local node 0..3 (one wave per node)
    int o = tid & 63;     // output column
    int node = blockIdx.x * 4 + r;
    if (node >= n) return;
    float inv = 1.0f / fmaxf(deg[node], 1.0f);
    float acc = b2[o];
    #pragma unroll
    for (int j = 0; j < HID; ++j) {
        float hv = h[(size_t)node * HID + j];
        float av = agg2[(size_t)node * HID + j] * inv;
        acc += hv * lws[j][o] + av * lwn[j][o];
    }
    out[(size_t)node * OUT + o] = acc;
}

extern "C" void kernel_launch(void* const* d_in, const int* in_sizes, int n_in,
                              void* d_out, int out_size, void* d_ws, size_t ws_size,
                              hipStream_t stream) {
    const float* x   = (const float*)d_in[0];
    const int*   src = (const int*)d_in[1];
    const int*   dst = (const int*)d_in[2];
    const float* Ws1 = (const float*)d_in[3];
    const float* Wn1 = (const float*)d_in[4];
    const float* b1  = (const float*)d_in[5];
    const float* Ws2 = (const float*)d_in[6];
    const float* Wn2 = (const float*)d_in[7];
    const float* b2  = (const float*)d_in[8];
    float* out = (float*)d_out;

    int n = in_sizes[0] / IN;   // 50000
    int e = in_sizes[1];        // 800000

    // Workspace layout (floats): agg1[n*16] | agg2[n*16] | deg[n] | xsxn[n*32] | h[n*16]
    float* agg1 = (float*)d_ws;
    float* agg2 = agg1 + (size_t)n * HID;
    float* deg  = agg2 + (size_t)n * HID;
    float* xsxn = deg + n;
    float* h    = xsxn + (size_t)n * 32;

    // Zero the atomic accumulators every call (harness does not re-poison).
    hipMemsetAsync(d_ws, 0, (size_t)(2 * HID + 1) * n * sizeof(float), stream);

    k_proj1<<<(n + 7) / 8, 256, 0, stream>>>(x, Ws1, Wn1, xsxn, n);

    int nthreads_sc = e * 16;
    int nblk_sc = (nthreads_sc + 255) / 256;
    k_scatter<<<nblk_sc, 256, 0, stream>>>(src, dst, xsxn, 32, 16, agg1, deg, e);

    k_finish1<<<(n * HID + 255) / 256, 256, 0, stream>>>(xsxn, agg1, deg, b1, h, n);

    k_scatter<<<nblk_sc, 256, 0, stream>>>(src, dst, h, 16, 0, agg2, nullptr, e);

    k_out<<<(n + 3) / 4, 256, 0, stream>>>(h, agg2, deg, Ws2, Wn2, b2, out, n);
}